// Round 3
// baseline (1453.765 us; speedup 1.0000x reference)
//
#include <hip/hip_runtime.h>

#define S_ 512
#define K_ 512
#define Q_ 64
#define D_ 256
#define H_ 8
#define SK_ (S_*K_)   // 262144
#define SQ_ (S_*Q_)   // 32768

typedef float f32x4 __attribute__((ext_vector_type(4)));
typedef short bf16x8 __attribute__((ext_vector_type(8)));
typedef short bf16x4 __attribute__((ext_vector_type(4)));

__device__ __forceinline__ short f2bf(float f) {
  unsigned u = __builtin_bit_cast(unsigned, f);
  u += 0x7fffu + ((u >> 16) & 1u);
  return (short)(u >> 16);
}
__device__ __forceinline__ float bf2f(short s) {
  unsigned u = ((unsigned)(unsigned short)s) << 16;
  return __builtin_bit_cast(float, u);
}

__device__ __forceinline__ void async_copy16(short* lds, const short* g) {
  __builtin_amdgcn_global_load_lds(
      (const __attribute__((address_space(1))) void*)g,
      (__attribute__((address_space(3))) void*)lds, 16, 0, 0);
}

// ---------------- weight fp32 -> bf16 ----------------
__global__ void cvt_w_kernel(const float* Wq, const float* Wk, const float* Wv,
                             const float* Wl, short* out) {
  int i = blockIdx.x * 256 + threadIdx.x;
  const float* src = (i < 65536) ? Wq : (i < 131072) ? Wk : (i < 196608) ? Wv : Wl;
  out[i] = f2bf(src[i & 65535]);
}

// ---------------- fused gather + K-proj + V-proj + passthrough-out ----------
// Block = 64 rows (32KB LDS -> 4 blocks/CU). Gather: load all 16 x-vectors
// first (src[8]/xv[8][2] keep them in flight), convert to bf16 into LDS,
// and stream the ORIGINAL fp32 straight to out (nontemporal): this replaces
// the old expand_kernel and kb buffer entirely.
// Then two MFMA passes over the same A tile:
// pass 0: Wk -> Kt[s][h][key][dh]; pass 1: Wv -> Vt[s][h][dh][key].
__global__ __launch_bounds__(256, 4) void gkv_kernel(const float* x, const int* tid,
                                                     const short* Wkb, const float* bkb,
                                                     const short* Wvb, const float* bvb,
                                                     short* Kt, short* Vt, float* out) {
  __shared__ short As[64 * 256];   // 32 KB
  int t = threadIdx.x;
  int w = t >> 6, lane = t & 63, quad = lane >> 4, l16 = lane & 15;
  int rbase0 = blockIdx.x * 64;
  int colbase = w * 64;

  // gather: 8 iters x 256 threads, 32 threads per row (1KB fp32 row-halves)
  int src[8];
#pragma unroll
  for (int i = 0; i < 8; i++) src[i] = tid[rbase0 + ((i * 256 + t) >> 5)];
  f32x4 xv[8][2];
#pragma unroll
  for (int i = 0; i < 8; i++) {
    int c = (i * 256 + t) & 31;
    const float* xp = x + (size_t)src[i] * 256 + c * 8;
    xv[i][0] = *(const f32x4*)xp;
    xv[i][1] = *(const f32x4*)(xp + 4);
  }
#pragma unroll
  for (int i = 0; i < 8; i++) {
    int g = i * 256 + t;
    int row = g >> 5, c = g & 31;
    int m = rbase0 + row;
    // passthrough: out row = exact fp32 x row (nontemporal stream)
    float* op = out + (size_t)m * 256 + c * 8;
    __builtin_nontemporal_store(xv[i][0], (f32x4*)op);
    __builtin_nontemporal_store(xv[i][1], (f32x4*)(op + 4));
    bf16x8 o;
#pragma unroll
    for (int j = 0; j < 4; j++) { o[j] = f2bf(xv[i][0][j]); o[j + 4] = f2bf(xv[i][1][j]); }
    *(bf16x8*)(As + row * 256 + (c ^ (row & 15)) * 8) = o;
  }
  __syncthreads();

#pragma unroll 1   // keep rolled: one 128-VGPR B-fragment set live at a time
  for (int p = 0; p < 2; p++) {
    const short* Wb = p ? Wvb : Wkb;
    const float* bias = p ? bvb : bkb;
    bf16x8 b[4][8];
#pragma unroll
    for (int nt = 0; nt < 4; nt++)
#pragma unroll
      for (int kk = 0; kk < 8; kk++)
        b[nt][kk] = *(const bf16x8*)(Wb + (colbase + nt * 16 + l16) * 256 + kk * 32 + quad * 8);
    float bv4[4];
#pragma unroll
    for (int nt = 0; nt < 4; nt++) bv4[nt] = bias[colbase + nt * 16 + l16];

    for (int mt = 0; mt < 4; mt++) {
      bf16x8 a[8];
#pragma unroll
      for (int kk = 0; kk < 8; kk++)
        a[kk] = *(const bf16x8*)(As + (mt * 16 + l16) * 256 + (((kk * 4 + quad) ^ l16) * 8));
      f32x4 acc[4];
#pragma unroll
      for (int nt = 0; nt < 4; nt++) acc[nt] = (f32x4){bv4[nt], bv4[nt], bv4[nt], bv4[nt]};
#pragma unroll
      for (int kk = 0; kk < 8; kk++)
#pragma unroll
        for (int nt = 0; nt < 4; nt++)
          acc[nt] = __builtin_amdgcn_mfma_f32_16x16x32_bf16(a[kk], b[nt][kk], acc[nt], 0, 0, 0);

      int rbase = rbase0 + mt * 16;
      int s = rbase >> 9;
      int keyb = (rbase & 511) + quad * 4;
      if (p == 0) {   // Kt[s][h][key][dh]
#pragma unroll
        for (int nt = 0; nt < 4; nt++) {
          int col = colbase + nt * 16 + l16;
          int h = col >> 5, dh = col & 31;
          size_t basek = ((size_t)(s * 8 + h) * 512 + keyb) * 32 + dh;
#pragma unroll
          for (int r = 0; r < 4; r++) Kt[basek + (size_t)r * 32] = f2bf(acc[nt][r]);
        }
      } else {        // Vt[s][h][dh][key]
#pragma unroll
        for (int nt = 0; nt < 4; nt++) {
          int col = colbase + nt * 16 + l16;
          int h = col >> 5, dh = col & 31;
          bf16x4 pk;
#pragma unroll
          for (int r = 0; r < 4; r++) pk[r] = f2bf(acc[nt][r]);
          *(bf16x4*)(Vt + ((((size_t)s * 8 + h) * 32 + dh) << 9) + keyb) = pk;
        }
      }
    }
  }
}

// ---------------- GEMM: C[M x 256] = A @ W^T + bias ----------------
// INDEXED=0: A bf16, LDS-staged via global_load_lds.
// INDEXED=1: A row m = x[tid[(m>>6)*512 + aid[m]]], fp32 gathered + converted
//            in registers (two-level indirection, no kb buffer).
template<int INDEXED>
__global__ __launch_bounds__(256, 2) void gemm2_kernel(const short* A, const float* x,
                                                       const int* tid, const int* aid,
                                                       const short* Wb, const float* bias,
                                                       short* Cp) {
  __shared__ short As[128 * 256];   // 64 KB
  int t = threadIdx.x;
  int w = t >> 6, lane = t & 63;
  int quad = lane >> 4, l16 = lane & 15;
  int rbase0 = blockIdx.x * 128;
  int colbase = w * 64;

  bf16x8 b[4][8];
#pragma unroll
  for (int nt = 0; nt < 4; nt++)
#pragma unroll
    for (int kk = 0; kk < 8; kk++)
      b[nt][kk] = *(const bf16x8*)(Wb + (colbase + nt * 16 + l16) * 256 + kk * 32 + quad * 8);
  float bv[4];
#pragma unroll
  for (int nt = 0; nt < 4; nt++) bv[nt] = bias[colbase + nt * 16 + l16];

  if (INDEXED) {
#pragma unroll
    for (int i = 0; i < 16; i++) {
      int g = i * 256 + t;
      int row = g >> 5, c = g & 31;
      int m = rbase0 + row;
      int s = m >> 6;
      int srcr = tid[(s << 9) + aid[m]];
      const float* xp = x + (size_t)srcr * 256 + c * 8;
      f32x4 v0 = *(const f32x4*)xp;
      f32x4 v1 = *(const f32x4*)(xp + 4);
      bf16x8 o;
#pragma unroll
      for (int j = 0; j < 4; j++) { o[j] = f2bf(v0[j]); o[j + 4] = f2bf(v1[j]); }
      *(bf16x8*)(As + row * 256 + (c ^ (row & 15)) * 8) = o;
    }
  } else {
    int cc = lane & 31;
#pragma unroll
    for (int i = 0; i < 16; i++) {
      int chunkLinear = w * 1024 + i * 64 + lane;
      int row = chunkLinear >> 5;
      int c = cc ^ (row & 15);                 // XOR swizzle (involutive)
      int m = rbase0 + row;
      async_copy16(As + (size_t)(w * 1024 + i * 64) * 8,
                   A + (size_t)m * 256 + c * 8);
    }
  }
  __syncthreads();

  for (int mt = 0; mt < 8; mt++) {
    bf16x8 a[8];
#pragma unroll
    for (int kk = 0; kk < 8; kk++)
      a[kk] = *(const bf16x8*)(As + (mt * 16 + l16) * 256 + (((kk * 4 + quad) ^ l16) * 8));
    f32x4 acc[4];
#pragma unroll
    for (int nt = 0; nt < 4; nt++) acc[nt] = (f32x4){bv[nt], bv[nt], bv[nt], bv[nt]};
#pragma unroll
    for (int kk = 0; kk < 8; kk++)
#pragma unroll
      for (int nt = 0; nt < 4; nt++)
        acc[nt] = __builtin_amdgcn_mfma_f32_16x16x32_bf16(a[kk], b[nt][kk], acc[nt], 0, 0, 0);

    int rbase = rbase0 + mt * 16;
#pragma unroll
    for (int nt = 0; nt < 4; nt++) {
      int col = colbase + nt * 16 + l16;
#pragma unroll
      for (int r = 0; r < 4; r++)
        Cp[(size_t)(rbase + quad * 4 + r) * 256 + col] = f2bf(acc[nt][r]);
    }
  }
}

// ---------------- attention per (s,h): 4 waves = 4 q-tiles of 16 ----------------
// K (Kt layout, contiguous 32KB/block) and V (Vt layout, contiguous 32KB/block)
// staged into LDS via global_load_lds; K region reused as P buffer after QK.
__global__ __launch_bounds__(256, 2) void attn_kernel(const short* Qp, const short* Kt,
                                                      const short* Vt, float* aout) {
  __shared__ short ldsK[16384];   // 32KB: K [512 key][32 dh]; then P [4 w][16 q][256 key] swz
  __shared__ short ldsV[16384];   // 32KB: V [32 dh][512 key], xor-swizzled (^((dh&7)<<4))
  int bid = blockIdx.x;
  int s = bid >> 3, h = bid & 7;
  int w = threadIdx.x >> 6;
  int lane = threadIdx.x & 63;
  int quad = lane >> 4, l16 = lane & 15;

  const char* kb = (const char*)(Kt + ((size_t)bid << 14));
  const char* vb = (const char*)(Vt + ((size_t)bid << 14));
  char* lk = (char*)ldsK;
  char* lv = (char*)ldsV;

#pragma unroll
  for (int i = 0; i < 8; i++) {
    int ab = w * 8192 + i * 1024;        // wave-uniform LDS base (HW adds lane*16)
    int a = ab + lane * 16;
    async_copy16((short*)(lk + ab), (const short*)(kb + a));
    async_copy16((short*)(lv + ab), (const short*)(vb + (a ^ (((a >> 10) & 7) << 4))));
  }

  bf16x8 aq = *(const bf16x8*)(Qp + ((size_t)(s * 64 + w * 16 + l16)) * 256 + h * 32 + quad * 8);
  __syncthreads();

  f32x4 zero = (f32x4){0.f, 0.f, 0.f, 0.f};
  f32x4 sc[32];
#pragma unroll
  for (int nt = 0; nt < 32; nt++) {
    bf16x8 bk = *(const bf16x8*)(lk + (nt * 16 + l16) * 64 + quad * 16);
    sc[nt] = __builtin_amdgcn_mfma_f32_16x16x32_bf16(aq, bk, zero, 0, 0, 0);
  }

  float lsum[4];
#pragma unroll
  for (int r = 0; r < 4; r++) {
    float t[16];
#pragma unroll
    for (int i = 0; i < 16; i++) t[i] = fmaxf(sc[i][r], sc[i + 16][r]);
#pragma unroll
    for (int st = 8; st; st >>= 1)
#pragma unroll
      for (int i = 0; i < st; i++) t[i] = fmaxf(t[i], t[i + st]);
    float m = t[0];
#pragma unroll
    for (int off = 1; off < 16; off <<= 1) m = fmaxf(m, __shfl_xor(m, off, 64));
#pragma unroll
    for (int nt = 0; nt < 32; nt++) sc[nt][r] = __expf((sc[nt][r] - m) * 0.0625f);
    float u[16];
#pragma unroll
    for (int i = 0; i < 16; i++) u[i] = sc[i][r] + sc[i + 16][r];
#pragma unroll
    for (int st = 8; st; st >>= 1)
#pragma unroll
      for (int i = 0; i < st; i++) u[i] += u[i + st];
    float l = u[0];
#pragma unroll
    for (int off = 1; off < 16; off <<= 1) l += __shfl_xor(l, off, 64);
    lsum[r] = l;
  }

  __syncthreads();   // all waves done reading K before P overwrites ldsK

  f32x4 o[2] = {zero, zero};
#pragma unroll
  for (int half = 0; half < 2; half++) {
#pragma unroll
    for (int nt = 0; nt < 16; nt++) {
      int ntg = half * 16 + nt;
#pragma unroll
      for (int r = 0; r < 4; r++) {
        int q = quad * 4 + r;
        *(short*)(lk + w * 8192 + q * 512 + ((nt * 32 + l16 * 2) ^ ((q & 7) << 4))) =
            f2bf(sc[ntg][r]);
      }
    }
    // no barrier: P region is wave-private, ldsV is read-only after stage
#pragma unroll
    for (int kk = 0; kk < 8; kk++) {
      bf16x8 ap = *(const bf16x8*)(lk + w * 8192 + l16 * 512 +
                                   ((kk * 64 + quad * 16) ^ ((l16 & 7) << 4)));
#pragma unroll
      for (int nt2 = 0; nt2 < 2; nt2++) {
        int dh = nt2 * 16 + l16;
        const bf16x8* vp = (const bf16x8*)(lv + dh * 1024 +
            ((half * 512 + kk * 64 + quad * 16) ^ ((dh & 7) << 4)));
        o[nt2] = __builtin_amdgcn_mfma_f32_16x16x32_bf16(ap, *vp, o[nt2], 0, 0, 0);
      }
    }
  }

#pragma unroll
  for (int nt2 = 0; nt2 < 2; nt2++)
#pragma unroll
    for (int r = 0; r < 4; r++) {
      int q = w * 16 + quad * 4 + r;
      int dh = nt2 * 16 + l16;
      size_t oq = ((size_t)(s * 64 + q)) * 256 + h * 32 + dh;
      aout[oq] = bf2f(Qp[oq]) + o[nt2][r] / lsum[r];
    }
}

// ---------------- LN1: fp32 in -> bf16 out ----------------
__global__ void ln1_kernel(const float* ain, const float* g1, const float* b1, short* out) {
  int g = blockIdx.x * 256 + threadIdx.x;
  int row = g >> 6, lane = g & 63;
  f32x4 v = *(const f32x4*)(ain + (size_t)row * 256 + lane * 4);
  float s = v[0] + v[1] + v[2] + v[3];
  float s2 = v[0]*v[0] + v[1]*v[1] + v[2]*v[2] + v[3]*v[3];
#pragma unroll
  for (int off = 1; off < 64; off <<= 1) { s += __shfl_xor(s, off, 64); s2 += __shfl_xor(s2, off, 64); }
  float mu = s * (1.f / 256.f);
  float var = s2 * (1.f / 256.f) - mu * mu;
  float inv = rsqrtf(var + 1e-5f);
  f32x4 gv = *(const f32x4*)(g1 + lane * 4);
  f32x4 bv = *(const f32x4*)(b1 + lane * 4);
  bf16x4 ov;
#pragma unroll
  for (int j = 0; j < 4; j++) ov[j] = f2bf((v[j] - mu) * inv * gv[j] + bv[j]);
  *(bf16x4*)(out + (size_t)row * 256 + lane * 4) = ov;
}

// ---------------- LN2 + scatter-add into d_out ----------------
__global__ void ln2_kernel(const short* ln1, const short* tmp, const float* g2, const float* b2,
                           const int* aid, float* dout) {
  int g = blockIdx.x * 256 + threadIdx.x;
  int row = g >> 6, lane = g & 63;
  bf16x4 a = *(const bf16x4*)(ln1 + (size_t)row * 256 + lane * 4);
  bf16x4 t = *(const bf16x4*)(tmp + (size_t)row * 256 + lane * 4);
  float v[4];
#pragma unroll
  for (int j = 0; j < 4; j++) v[j] = bf2f(a[j]) + fmaxf(bf2f(t[j]), 0.f);
  float s = v[0] + v[1] + v[2] + v[3];
  float s2 = v[0]*v[0] + v[1]*v[1] + v[2]*v[2] + v[3]*v[3];
#pragma unroll
  for (int off = 1; off < 64; off <<= 1) { s += __shfl_xor(s, off, 64); s2 += __shfl_xor(s2, off, 64); }
  float mu = s * (1.f / 256.f);
  float var = s2 * (1.f / 256.f) - mu * mu;
  float inv = rsqrtf(var + 1e-5f);
  f32x4 gv = *(const f32x4*)(g2 + lane * 4);
  f32x4 bv = *(const f32x4*)(b2 + lane * 4);
  int sIdx = row >> 6;
  int tgt = aid[row];
  float* op = dout + ((size_t)(sIdx * 512 + tgt)) * 256 + lane * 4;
  f32x4 cur = *(f32x4*)op;
#pragma unroll
  for (int j = 0; j < 4; j++) cur[j] += (v[j] - mu) * inv * gv[j] + bv[j];
  *(f32x4*)op = cur;
}

extern "C" void kernel_launch(void* const* d_in, const int* in_sizes, int n_in,
                              void* d_out, int out_size, void* d_ws, size_t ws_size,
                              hipStream_t stream) {
  const float* x   = (const float*)d_in[0];
  const int* tid   = (const int*)d_in[1];
  const int* aid   = (const int*)d_in[2];
  const float* Wq  = (const float*)d_in[3];
  const float* bq  = (const float*)d_in[4];
  const float* Wk  = (const float*)d_in[5];
  const float* bk  = (const float*)d_in[6];
  const float* Wv  = (const float*)d_in[7];
  const float* bv  = (const float*)d_in[8];
  const float* g1  = (const float*)d_in[9];
  const float* b1  = (const float*)d_in[10];
  const float* Wl  = (const float*)d_in[11];
  const float* bl  = (const float*)d_in[12];
  const float* g2  = (const float*)d_in[13];
  const float* b2  = (const float*)d_in[14];
  float* out = (float*)d_out;

  // ws layout (~318 MB, ws is ~1 GiB per fillBuffer evidence):
  // Wb(0.5) | Kt(134) | Vt(134) | Qpb(16) | aout(33).
  // d_out carries final values from gkv (passthrough) onward; ln2 RMWs Q rows.
  char* base = (char*)d_ws;
  short* Wqb = (short*)base;
  short* Wkb = Wqb + 65536;
  short* Wvb = Wkb + 65536;
  short* Wlb = Wvb + 65536;
  size_t off = 4ull * 65536 * 2;
  short* Ktb  = (short*)(base + off); off += (size_t)SK_ * 256 * 2;
  short* Vtb  = (short*)(base + off); off += (size_t)SK_ * 256 * 2;
  short* Qpb  = (short*)(base + off); off += (size_t)SQ_ * 256 * 2;
  float* aout = (float*)(base + off); off += (size_t)SQ_ * 256 * 4;
  short* ln1b = Qpb;                       // Qp dead after attn
  short* tmpb = Ktb;                       // Kt dead after attn
  (void)ws_size; (void)in_sizes; (void)n_in; (void)out_size;

  cvt_w_kernel<<<1024, 256, 0, stream>>>(Wq, Wk, Wv, Wl, Wqb);
  gkv_kernel<<<SK_ / 64, 256, 0, stream>>>(x, tid, Wkb, bk, Wvb, bv, Ktb, Vtb, out);
  gemm2_kernel<1><<<SQ_ / 128, 256, 0, stream>>>(nullptr, x, tid, aid, Wqb, bq, Qpb);
  attn_kernel<<<S_ * H_, 256, 0, stream>>>(Qpb, Ktb, Vtb, aout);
  ln1_kernel<<<SQ_ / 4, 256, 0, stream>>>(aout, g1, b1, ln1b);
  gemm2_kernel<0><<<SQ_ / 128, 256, 0, stream>>>(ln1b, nullptr, nullptr, nullptr, Wlb, bl, tmpb);
  ln2_kernel<<<SQ_ / 4, 256, 0, stream>>>(ln1b, tmpb, g2, b2, aid, out);
}

// Round 4
// 733.275 us; speedup vs baseline: 1.9826x; 1.9826x over previous
//
#include <hip/hip_runtime.h>

#define S_ 512
#define K_ 512
#define Q_ 64
#define D_ 256
#define H_ 8
#define SK_ (S_*K_)   // 262144
#define SQ_ (S_*Q_)   // 32768

typedef float f32x4 __attribute__((ext_vector_type(4)));
typedef short bf16x8 __attribute__((ext_vector_type(8)));
typedef short bf16x4 __attribute__((ext_vector_type(4)));

__device__ __forceinline__ short f2bf(float f) {
  unsigned u = __builtin_bit_cast(unsigned, f);
  u += 0x7fffu + ((u >> 16) & 1u);
  return (short)(u >> 16);
}
__device__ __forceinline__ float bf2f(short s) {
  unsigned u = ((unsigned)(unsigned short)s) << 16;
  return __builtin_bit_cast(float, u);
}

__device__ __forceinline__ void async_copy16(short* lds, const short* g) {
  __builtin_amdgcn_global_load_lds(
      (const __attribute__((address_space(1))) void*)g,
      (__attribute__((address_space(3))) void*)lds, 16, 0, 0);
}

// ---------------- weight fp32 -> bf16 ----------------
__global__ void cvt_w_kernel(const float* Wq, const float* Wk, const float* Wv,
                             const float* Wl, short* out) {
  int i = blockIdx.x * 256 + threadIdx.x;
  const float* src = (i < 65536) ? Wq : (i < 131072) ? Wk : (i < 196608) ? Wv : Wl;
  out[i] = f2bf(src[i & 65535]);
}

// ---------------- fused gather + K-proj + V-proj + passthrough-out ----------
// Round-2 proven structure: 128-row tile, 64KB LDS, lb(256,2), per-iteration
// gather (low register pressure -> no spills; round-3's staged arrays at lb4
// clamped VGPR to 64 and spilled ~2.8GB to scratch).
// Gather phase also streams the exact fp32 x row to out (replaces expand).
// pass 0 (swapped operands): Wk -> Kt[s][h][key][dh], packed 8B stores.
// pass 1: Wv -> Vt[s][h][dh][key], packed 8B stores.
__global__ __launch_bounds__(256, 2) void gkv_kernel(const float* x, const int* tid,
                                                     const short* Wkb, const float* bkb,
                                                     const short* Wvb, const float* bvb,
                                                     short* Kt, short* Vt, float* out) {
  __shared__ short As[128 * 256];   // 64 KB
  int t = threadIdx.x;
  int w = t >> 6, lane = t & 63, quad = lane >> 4, l16 = lane & 15;
  int rbase0 = blockIdx.x * 128;
  int colbase = w * 64;

  // gather+convert: 32 threads per row (1KB fp32 row-halves), per-iter bodies
#pragma unroll
  for (int i = 0; i < 16; i++) {
    int g = i * 256 + t;
    int row = g >> 5, c = g & 31;
    int m = rbase0 + row;
    int src = tid[m];
    const float* xp = x + (size_t)src * 256 + c * 8;
    f32x4 v0 = *(const f32x4*)xp;
    f32x4 v1 = *(const f32x4*)(xp + 4);
    // passthrough: out row = exact fp32 x row (nontemporal stream)
    float* op = out + (size_t)m * 256 + c * 8;
    __builtin_nontemporal_store(v0, (f32x4*)op);
    __builtin_nontemporal_store(v1, (f32x4*)(op + 4));
    bf16x8 o;
#pragma unroll
    for (int j = 0; j < 4; j++) { o[j] = f2bf(v0[j]); o[j + 4] = f2bf(v1[j]); }
    *(bf16x8*)(As + row * 256 + (c ^ (row & 15)) * 8) = o;
  }
  __syncthreads();

#pragma unroll 1   // keep rolled: one 128-VGPR B-fragment set live at a time
  for (int p = 0; p < 2; p++) {
    const short* Wb = p ? Wvb : Wkb;
    const float* bias = p ? bvb : bkb;
    bf16x8 b[4][8];
#pragma unroll
    for (int nt = 0; nt < 4; nt++)
#pragma unroll
      for (int kk = 0; kk < 8; kk++)
        b[nt][kk] = *(const bf16x8*)(Wb + (colbase + nt * 16 + l16) * 256 + kk * 32 + quad * 8);

    for (int mt = 0; mt < 8; mt++) {
      bf16x8 a[8];
#pragma unroll
      for (int kk = 0; kk < 8; kk++)
        a[kk] = *(const bf16x8*)(As + (mt * 16 + l16) * 256 + (((kk * 4 + quad) ^ l16) * 8));
      int rbase = rbase0 + mt * 16;
      int s = rbase >> 9;

      if (p == 0) {
        // swapped operands: D = (W·A^T): D col (lane&15) = key, D row
        // (quad*4+r) = output col n -> lane packs 4 consecutive dh for 1 key.
        f32x4 acc[4];
#pragma unroll
        for (int nt = 0; nt < 4; nt++)
          acc[nt] = *(const f32x4*)(bias + colbase + nt * 16 + quad * 4);
#pragma unroll
        for (int kk = 0; kk < 8; kk++)
#pragma unroll
          for (int nt = 0; nt < 4; nt++)
            acc[nt] = __builtin_amdgcn_mfma_f32_16x16x32_bf16(b[nt][kk], a[kk], acc[nt], 0, 0, 0);
        int key = (rbase & 511) + l16;
#pragma unroll
        for (int nt = 0; nt < 4; nt++) {
          int n0 = colbase + nt * 16 + quad * 4;
          int h = n0 >> 5, dh = n0 & 31;
          bf16x4 pk;
#pragma unroll
          for (int r = 0; r < 4; r++) pk[r] = f2bf(acc[nt][r]);
          *(bf16x4*)(Kt + ((size_t)(s * 8 + h) * 512 + key) * 32 + dh) = pk;
        }
      } else {
        // normal operands: lane packs 4 consecutive keys for 1 dh.
        float bv4[4];
#pragma unroll
        for (int nt = 0; nt < 4; nt++) bv4[nt] = bias[colbase + nt * 16 + l16];
        f32x4 acc[4];
#pragma unroll
        for (int nt = 0; nt < 4; nt++) acc[nt] = (f32x4){bv4[nt], bv4[nt], bv4[nt], bv4[nt]};
#pragma unroll
        for (int kk = 0; kk < 8; kk++)
#pragma unroll
          for (int nt = 0; nt < 4; nt++)
            acc[nt] = __builtin_amdgcn_mfma_f32_16x16x32_bf16(a[kk], b[nt][kk], acc[nt], 0, 0, 0);
        int keyb = (rbase & 511) + quad * 4;
#pragma unroll
        for (int nt = 0; nt < 4; nt++) {
          int col = colbase + nt * 16 + l16;
          int h = col >> 5, dh = col & 31;
          bf16x4 pk;
#pragma unroll
          for (int r = 0; r < 4; r++) pk[r] = f2bf(acc[nt][r]);
          *(bf16x4*)(Vt + ((((size_t)s * 8 + h) * 32 + dh) << 9) + keyb) = pk;
        }
      }
    }
  }
}

// ---------------- GEMM: C[M x 256] = A @ W^T + bias ----------------
// INDEXED=0: A bf16, LDS-staged via global_load_lds.
// INDEXED=1: A row m = x[tid[(m>>6)*512 + aid[m]]], fp32 gathered + converted
//            in registers (two-level indirection, no kb buffer).
template<int INDEXED>
__global__ __launch_bounds__(256, 2) void gemm2_kernel(const short* A, const float* x,
                                                       const int* tid, const int* aid,
                                                       const short* Wb, const float* bias,
                                                       short* Cp) {
  __shared__ short As[128 * 256];   // 64 KB
  int t = threadIdx.x;
  int w = t >> 6, lane = t & 63;
  int quad = lane >> 4, l16 = lane & 15;
  int rbase0 = blockIdx.x * 128;
  int colbase = w * 64;

  bf16x8 b[4][8];
#pragma unroll
  for (int nt = 0; nt < 4; nt++)
#pragma unroll
    for (int kk = 0; kk < 8; kk++)
      b[nt][kk] = *(const bf16x8*)(Wb + (colbase + nt * 16 + l16) * 256 + kk * 32 + quad * 8);
  float bv[4];
#pragma unroll
  for (int nt = 0; nt < 4; nt++) bv[nt] = bias[colbase + nt * 16 + l16];

  if (INDEXED) {
#pragma unroll
    for (int i = 0; i < 16; i++) {
      int g = i * 256 + t;
      int row = g >> 5, c = g & 31;
      int m = rbase0 + row;
      int s = m >> 6;
      int srcr = tid[(s << 9) + aid[m]];
      const float* xp = x + (size_t)srcr * 256 + c * 8;
      f32x4 v0 = *(const f32x4*)xp;
      f32x4 v1 = *(const f32x4*)(xp + 4);
      bf16x8 o;
#pragma unroll
      for (int j = 0; j < 4; j++) { o[j] = f2bf(v0[j]); o[j + 4] = f2bf(v1[j]); }
      *(bf16x8*)(As + row * 256 + (c ^ (row & 15)) * 8) = o;
    }
  } else {
    int cc = lane & 31;
#pragma unroll
    for (int i = 0; i < 16; i++) {
      int chunkLinear = w * 1024 + i * 64 + lane;
      int row = chunkLinear >> 5;
      int c = cc ^ (row & 15);                 // XOR swizzle (involutive)
      int m = rbase0 + row;
      async_copy16(As + (size_t)(w * 1024 + i * 64) * 8,
                   A + (size_t)m * 256 + c * 8);
    }
  }
  __syncthreads();

  for (int mt = 0; mt < 8; mt++) {
    bf16x8 a[8];
#pragma unroll
    for (int kk = 0; kk < 8; kk++)
      a[kk] = *(const bf16x8*)(As + (mt * 16 + l16) * 256 + (((kk * 4 + quad) ^ l16) * 8));
    f32x4 acc[4];
#pragma unroll
    for (int nt = 0; nt < 4; nt++) acc[nt] = (f32x4){bv[nt], bv[nt], bv[nt], bv[nt]};
#pragma unroll
    for (int kk = 0; kk < 8; kk++)
#pragma unroll
      for (int nt = 0; nt < 4; nt++)
        acc[nt] = __builtin_amdgcn_mfma_f32_16x16x32_bf16(a[kk], b[nt][kk], acc[nt], 0, 0, 0);

    int rbase = rbase0 + mt * 16;
#pragma unroll
    for (int nt = 0; nt < 4; nt++) {
      int col = colbase + nt * 16 + l16;
#pragma unroll
      for (int r = 0; r < 4; r++)
        Cp[(size_t)(rbase + quad * 4 + r) * 256 + col] = f2bf(acc[nt][r]);
    }
  }
}

// ---------------- attention per (s,h): 4 waves = 4 q-tiles of 16 ----------------
// K (Kt layout, contiguous 32KB/block) and V (Vt layout, contiguous 32KB/block)
// staged into LDS via global_load_lds; K region reused as P buffer after QK.
__global__ __launch_bounds__(256, 2) void attn_kernel(const short* Qp, const short* Kt,
                                                      const short* Vt, float* aout) {
  __shared__ short ldsK[16384];   // 32KB: K [512 key][32 dh]; then P [4 w][16 q][256 key] swz
  __shared__ short ldsV[16384];   // 32KB: V [32 dh][512 key], xor-swizzled (^((dh&7)<<4))
  int bid = blockIdx.x;
  int s = bid >> 3, h = bid & 7;
  int w = threadIdx.x >> 6;
  int lane = threadIdx.x & 63;
  int quad = lane >> 4, l16 = lane & 15;

  const char* kb = (const char*)(Kt + ((size_t)bid << 14));
  const char* vb = (const char*)(Vt + ((size_t)bid << 14));
  char* lk = (char*)ldsK;
  char* lv = (char*)ldsV;

#pragma unroll
  for (int i = 0; i < 8; i++) {
    int ab = w * 8192 + i * 1024;        // wave-uniform LDS base (HW adds lane*16)
    int a = ab + lane * 16;
    async_copy16((short*)(lk + ab), (const short*)(kb + a));
    async_copy16((short*)(lv + ab), (const short*)(vb + (a ^ (((a >> 10) & 7) << 4))));
  }

  bf16x8 aq = *(const bf16x8*)(Qp + ((size_t)(s * 64 + w * 16 + l16)) * 256 + h * 32 + quad * 8);
  __syncthreads();

  f32x4 zero = (f32x4){0.f, 0.f, 0.f, 0.f};
  f32x4 sc[32];
#pragma unroll
  for (int nt = 0; nt < 32; nt++) {
    bf16x8 bk = *(const bf16x8*)(lk + (nt * 16 + l16) * 64 + quad * 16);
    sc[nt] = __builtin_amdgcn_mfma_f32_16x16x32_bf16(aq, bk, zero, 0, 0, 0);
  }

  float lsum[4];
#pragma unroll
  for (int r = 0; r < 4; r++) {
    float t[16];
#pragma unroll
    for (int i = 0; i < 16; i++) t[i] = fmaxf(sc[i][r], sc[i + 16][r]);
#pragma unroll
    for (int st = 8; st; st >>= 1)
#pragma unroll
      for (int i = 0; i < st; i++) t[i] = fmaxf(t[i], t[i + st]);
    float m = t[0];
#pragma unroll
    for (int off = 1; off < 16; off <<= 1) m = fmaxf(m, __shfl_xor(m, off, 64));
#pragma unroll
    for (int nt = 0; nt < 32; nt++) sc[nt][r] = __expf((sc[nt][r] - m) * 0.0625f);
    float u[16];
#pragma unroll
    for (int i = 0; i < 16; i++) u[i] = sc[i][r] + sc[i + 16][r];
#pragma unroll
    for (int st = 8; st; st >>= 1)
#pragma unroll
      for (int i = 0; i < st; i++) u[i] += u[i + st];
    float l = u[0];
#pragma unroll
    for (int off = 1; off < 16; off <<= 1) l += __shfl_xor(l, off, 64);
    lsum[r] = l;
  }

  __syncthreads();   // all waves done reading K before P overwrites ldsK

  f32x4 o[2] = {zero, zero};
#pragma unroll
  for (int half = 0; half < 2; half++) {
#pragma unroll
    for (int nt = 0; nt < 16; nt++) {
      int ntg = half * 16 + nt;
#pragma unroll
      for (int r = 0; r < 4; r++) {
        int q = quad * 4 + r;
        *(short*)(lk + w * 8192 + q * 512 + ((nt * 32 + l16 * 2) ^ ((q & 7) << 4))) =
            f2bf(sc[ntg][r]);
      }
    }
    // no barrier: P region is wave-private, ldsV is read-only after stage
#pragma unroll
    for (int kk = 0; kk < 8; kk++) {
      bf16x8 ap = *(const bf16x8*)(lk + w * 8192 + l16 * 512 +
                                   ((kk * 64 + quad * 16) ^ ((l16 & 7) << 4)));
#pragma unroll
      for (int nt2 = 0; nt2 < 2; nt2++) {
        int dh = nt2 * 16 + l16;
        const bf16x8* vp = (const bf16x8*)(lv + dh * 1024 +
            ((half * 512 + kk * 64 + quad * 16) ^ ((dh & 7) << 4)));
        o[nt2] = __builtin_amdgcn_mfma_f32_16x16x32_bf16(ap, *vp, o[nt2], 0, 0, 0);
      }
    }
  }

#pragma unroll
  for (int nt2 = 0; nt2 < 2; nt2++)
#pragma unroll
    for (int r = 0; r < 4; r++) {
      int q = w * 16 + quad * 4 + r;
      int dh = nt2 * 16 + l16;
      size_t oq = ((size_t)(s * 64 + q)) * 256 + h * 32 + dh;
      aout[oq] = bf2f(Qp[oq]) + o[nt2][r] / lsum[r];
    }
}

// ---------------- LN1: fp32 in -> bf16 out ----------------
__global__ void ln1_kernel(const float* ain, const float* g1, const float* b1, short* out) {
  int g = blockIdx.x * 256 + threadIdx.x;
  int row = g >> 6, lane = g & 63;
  f32x4 v = *(const f32x4*)(ain + (size_t)row * 256 + lane * 4);
  float s = v[0] + v[1] + v[2] + v[3];
  float s2 = v[0]*v[0] + v[1]*v[1] + v[2]*v[2] + v[3]*v[3];
#pragma unroll
  for (int off = 1; off < 64; off <<= 1) { s += __shfl_xor(s, off, 64); s2 += __shfl_xor(s2, off, 64); }
  float mu = s * (1.f / 256.f);
  float var = s2 * (1.f / 256.f) - mu * mu;
  float inv = rsqrtf(var + 1e-5f);
  f32x4 gv = *(const f32x4*)(g1 + lane * 4);
  f32x4 bv = *(const f32x4*)(b1 + lane * 4);
  bf16x4 ov;
#pragma unroll
  for (int j = 0; j < 4; j++) ov[j] = f2bf((v[j] - mu) * inv * gv[j] + bv[j]);
  *(bf16x4*)(out + (size_t)row * 256 + lane * 4) = ov;
}

// ---------------- LN2 + scatter-add into d_out ----------------
__global__ void ln2_kernel(const short* ln1, const short* tmp, const float* g2, const float* b2,
                           const int* aid, float* dout) {
  int g = blockIdx.x * 256 + threadIdx.x;
  int row = g >> 6, lane = g & 63;
  bf16x4 a = *(const bf16x4*)(ln1 + (size_t)row * 256 + lane * 4);
  bf16x4 t = *(const bf16x4*)(tmp + (size_t)row * 256 + lane * 4);
  float v[4];
#pragma unroll
  for (int j = 0; j < 4; j++) v[j] = bf2f(a[j]) + fmaxf(bf2f(t[j]), 0.f);
  float s = v[0] + v[1] + v[2] + v[3];
  float s2 = v[0]*v[0] + v[1]*v[1] + v[2]*v[2] + v[3]*v[3];
#pragma unroll
  for (int off = 1; off < 64; off <<= 1) { s += __shfl_xor(s, off, 64); s2 += __shfl_xor(s2, off, 64); }
  float mu = s * (1.f / 256.f);
  float var = s2 * (1.f / 256.f) - mu * mu;
  float inv = rsqrtf(var + 1e-5f);
  f32x4 gv = *(const f32x4*)(g2 + lane * 4);
  f32x4 bv = *(const f32x4*)(b2 + lane * 4);
  int sIdx = row >> 6;
  int tgt = aid[row];
  float* op = dout + ((size_t)(sIdx * 512 + tgt)) * 256 + lane * 4;
  f32x4 cur = *(f32x4*)op;
#pragma unroll
  for (int j = 0; j < 4; j++) cur[j] += (v[j] - mu) * inv * gv[j] + bv[j];
  *(f32x4*)op = cur;
}

extern "C" void kernel_launch(void* const* d_in, const int* in_sizes, int n_in,
                              void* d_out, int out_size, void* d_ws, size_t ws_size,
                              hipStream_t stream) {
  const float* x   = (const float*)d_in[0];
  const int* tid   = (const int*)d_in[1];
  const int* aid   = (const int*)d_in[2];
  const float* Wq  = (const float*)d_in[3];
  const float* bq  = (const float*)d_in[4];
  const float* Wk  = (const float*)d_in[5];
  const float* bk  = (const float*)d_in[6];
  const float* Wv  = (const float*)d_in[7];
  const float* bv  = (const float*)d_in[8];
  const float* g1  = (const float*)d_in[9];
  const float* b1  = (const float*)d_in[10];
  const float* Wl  = (const float*)d_in[11];
  const float* bl  = (const float*)d_in[12];
  const float* g2  = (const float*)d_in[13];
  const float* b2  = (const float*)d_in[14];
  float* out = (float*)d_out;

  // ws layout: Wb(0.5) | Kt(134) | Vt(134) | Qpb(16) | aout(33) MB.
  // d_out carries final values from gkv (passthrough) onward; ln2 RMWs Q rows.
  char* base = (char*)d_ws;
  short* Wqb = (short*)base;
  short* Wkb = Wqb + 65536;
  short* Wvb = Wkb + 65536;
  short* Wlb = Wvb + 65536;
  size_t off = 4ull * 65536 * 2;
  short* Ktb  = (short*)(base + off); off += (size_t)SK_ * 256 * 2;
  short* Vtb  = (short*)(base + off); off += (size_t)SK_ * 256 * 2;
  short* Qpb  = (short*)(base + off); off += (size_t)SQ_ * 256 * 2;
  float* aout = (float*)(base + off); off += (size_t)SQ_ * 256 * 4;
  short* ln1b = Qpb;                       // Qp dead after attn
  short* tmpb = Ktb;                       // Kt dead after attn
  (void)ws_size; (void)in_sizes; (void)n_in; (void)out_size;

  cvt_w_kernel<<<1024, 256, 0, stream>>>(Wq, Wk, Wv, Wl, Wqb);
  gkv_kernel<<<SK_ / 128, 256, 0, stream>>>(x, tid, Wkb, bk, Wvb, bv, Ktb, Vtb, out);
  gemm2_kernel<1><<<SQ_ / 128, 256, 0, stream>>>(nullptr, x, tid, aid, Wqb, bq, Qpb);
  attn_kernel<<<S_ * H_, 256, 0, stream>>>(Qpb, Ktb, Vtb, aout);
  ln1_kernel<<<SQ_ / 4, 256, 0, stream>>>(aout, g1, b1, ln1b);
  gemm2_kernel<0><<<SQ_ / 128, 256, 0, stream>>>(ln1b, nullptr, nullptr, nullptr, Wlb, bl, tmpb);
  ln2_kernel<<<SQ_ / 4, 256, 0, stream>>>(ln1b, tmpb, g2, b2, aid, out);
}